// Round 9
// baseline (170.021 us; speedup 1.0000x reference)
//
#include <hip/hip_runtime.h>

#define NM    4096
#define NPTS  131072
#define CAP   128
#define NV    4            // voxels per persistent 1-wave block
#define NBLK  (NM / NV)    // 1024 blocks = 4 blocks/CU, all co-resident (LDS cap 6)

typedef _Float16 h8 __attribute__((ext_vector_type(8)));
typedef _Float16 h2 __attribute__((ext_vector_type(2)));
typedef float    f4 __attribute__((ext_vector_type(4)));
typedef int      i4 __attribute__((ext_vector_type(4)));

#define MF(a, b, c) __builtin_amdgcn_mfma_f32_16x16x32_f16((a), (b), (c), 0, 0, 0)

#if __has_builtin(__builtin_amdgcn_global_load_lds)
#define USE_DMA 1
#else
#define USE_DMA 0
#endif

static __device__ inline h2 pk(float a, float b) {
    return __builtin_bit_cast(h2, __builtin_amdgcn_cvt_pkrtz(a, b));
}

static __device__ inline h8 pack8(float u0, float u1, float u2, float u3,
                                  float u4, float u5, float u6, float u7) {
    i4 t;
    t[0] = __builtin_bit_cast(int, pk(u0, u1));
    t[1] = __builtin_bit_cast(int, pk(u2, u3));
    t[2] = __builtin_bit_cast(int, pk(u4, u5));
    t[3] = __builtin_bit_cast(int, pk(u6, u7));
    return __builtin_bit_cast(h8, t);
}

// 8 guarded f16 from an fp32 row in LDS (reads unconditional + select).
static __device__ inline h8 lds_row8(const float* __restrict__ X, int base,
                                     int d0, int lim) {
    float u[8];
    #pragma unroll
    for (int jj = 0; jj < 8; jj++) {
        int d = d0 + jj;
        float raw = X[base + d];          // always in-bounds of the 3040-f region
        u[jj] = (d < lim) ? raw : 0.f;
    }
    return pack8(u[0], u[1], u[2], u[3], u[4], u[5], u[6], u[7]);
}

// aligned 8-float (32B) run in LDS -> h8 (two ds_read_b128)
static __device__ inline h8 lds_row8a(const float* __restrict__ X, int off) {
    f4 v0 = *(const f4*)(X + off);
    f4 v1 = *(const f4*)(X + off + 4);
    return pack8(v0[0], v0[1], v0[2], v0[3], v1[0], v1[1], v1[2], v1[3]);
}

// 8 guarded f16 from a global fp32 row (fallback path, no DMA builtin).
static __device__ inline h8 load_row8(const float* __restrict__ rb, int d0, int lim) {
    float u[8];
    #pragma unroll
    for (int jj = 0; jj < 8; jj++) {
        int d = d0 + jj;
        u[jj] = (d < lim) ? rb[d] : 0.f;
    }
    return pack8(u[0], u[1], u[2], u[3], u[4], u[5], u[6], u[7]);
}

// NeRF frequency-encoding dim d of (x,y,z); 0 for d >= lim.
static __device__ inline float encdim(int d, int lim, float x, float y, float z) {
    int tt = d - 3;
    int k  = tt / 6;
    int r  = tt - 6 * k;
    float p = x;
    p = (r == 1 || r == 4) ? y : p;
    p = (r == 2 || r == 5) ? z : p;
    float f   = __int_as_float((k + 127) << 23);   // 2^k
    float arg = p * f + ((r >= 3) ? 1.57079632679f : 0.f);  // cos = sin(+pi/2)
    float sv  = __sinf(arg);
    float raw = (d == 0) ? x : ((d == 1) ? y : z);
    float val = (d < 3) ? raw : sv;
    return (d < lim) ? val : 0.f;
}

// D-frag pair -> B-frag (verified lineage; d1[3] typo from R14 fixed in R15).
static __device__ inline h8 makeB(f4 d0, f4 d1, int quad, int col) {
    int laneA = ((quad & 1) * 2) * 16 + col;
    int laneB = laneA + 16;
    float a0 = __shfl(d0[0], laneA), b0 = __shfl(d1[0], laneA);
    float a1 = __shfl(d0[1], laneA), b1 = __shfl(d1[1], laneA);
    float a2 = __shfl(d0[2], laneA), b2 = __shfl(d1[2], laneA);
    float a3 = __shfl(d0[3], laneA), b3 = __shfl(d1[3], laneA);
    float a4 = __shfl(d0[0], laneB), b4 = __shfl(d1[0], laneB);
    float a5 = __shfl(d0[1], laneB), b5 = __shfl(d1[1], laneB);
    float a6 = __shfl(d0[2], laneB), b6 = __shfl(d1[2], laneB);
    float a7 = __shfl(d0[3], laneB), b7 = __shfl(d1[3], laneB);
    bool hi = quad >= 2;
    return pack8(hi ? b0 : a0, hi ? b1 : a1, hi ? b2 : a2, hi ? b3 : a3,
                 hi ? b4 : a4, hi ? b5 : a5, hi ? b6 : a6, hi ? b7 : a7);
}

static __device__ inline f4 relu4(f4 a) {
    f4 r;
    r[0] = fmaxf(a[0], 0.f); r[1] = fmaxf(a[1], 0.f);
    r[2] = fmaxf(a[2], 0.f); r[3] = fmaxf(a[3], 0.f);
    return r;
}

#if USE_DMA
static __device__ inline void dma16(const float* g, const float* l) {
    __builtin_amdgcn_global_load_lds(
        (const __attribute__((address_space(1))) void*)g,
        (__attribute__((address_space(3))) void*)l, 16, 0, 0);
}
#endif

__global__ __launch_bounds__(256) void k_bucket(const float* __restrict__ pts,
                                                int* __restrict__ count,
                                                int* __restrict__ plist) {
    int n = blockIdx.x * 256 + threadIdx.x;
    if (n >= NPTS) return;
    float x = pts[3 * n + 0], y = pts[3 * n + 1], z = pts[3 * n + 2];
    int ix = (int)fminf(fmaxf(x * 16.f, 0.f), 15.f);
    int iy = (int)fminf(fmaxf(y * 16.f, 0.f), 15.f);
    int iz = (int)fminf(fmaxf(z * 16.f, 0.f), 15.f);
    int v = (ix << 8) | (iy << 4) | iz;
    int pos = atomicAdd(&count[v], 1);
    if (pos < CAP) plist[v * CAP + pos] = n;
}

// R17: persistent 1-wave blocks, NV=4 voxels, double-buffered LDS, ZERO
// barriers, cross-voxel DMA pipeline.
// R0..R16 post-mortem: all five schedules pin at ~41-48us because every one
// fully drains its memory stream (vmcnt(0)/barrier) then computes with zero
// bytes in flight; with residency pinned ~5 waves/CU the chip equilibrates
// at ~2.5 TB/s delivered. Fix: keep each wave's stream alive ACROSS voxels.
// Steady-state schedule per voxel iv (buffer cur):
//   TOP: vmcnt(0) [A(iv)+prefetched meta/pts landed] ; snapshot state
//   unpackA(X[cur]) ; ch1-gather(iv) ; pf_meta(iv+1)=count/plist/biases
//   lgkmcnt(0) [WAR: A-reads retired] ; B-DMA(iv)->X[cur]
//   encode ch0 ; phaseA (L0/L1, A-frags only)        <- covers B flight
//   vmcnt(0) [B+ch1+meta landed; A(iv+1) NOT yet issued -> nothing lost]
//   unpackB(X[cur]) ; pf_pts(iv+1) [plist landed ^] ; A-DMA(iv+1)->X[cur^1]
//   phaseB ch0 ; ch1 ; ch2+ (inline gathers)         <- covers A(iv+1) flight
// All waits are vmcnt(0) at full-drain points or compiler-tracked counted
// waits (pf_pts dependence) -> no fragile manual vmcnt(N). Double buffer
// makes every DMA target dead w.r.t. outstanding ds_reads (results consumed).
// sched_barrier(0) pins ordering around each inline wait (rule #18).
__global__ __launch_bounds__(64) void k_mlp(
    const float* __restrict__ pts, const float* __restrict__ vds,
    const float* __restrict__ w0g, const float* __restrict__ b0g,
    const float* __restrict__ w1g, const float* __restrict__ b1g,
    const float* __restrict__ fwg, const float* __restrict__ fbg,
    const float* __restrict__ swg, const float* __restrict__ sbg,
    const float* __restrict__ vwg, const float* __restrict__ vbg,
    const float* __restrict__ rwg, const float* __restrict__ rbg,
    const int* __restrict__ count, const int* __restrict__ plist,
    float* __restrict__ out) {
    __shared__ __align__(16) float X[2][3040];   // 24320 B -> 6 blocks/CU cap

    const int lane = threadIdx.x & 63;
    const int col  = lane & 15;
    const int quad = lane >> 4;
    const int k8   = quad * 8;
    const int vbase = blockIdx.x * NV;

#if USE_DMA
    auto dmaA = [&](int v, float* Xb) {          // w0@0 (2016), w1@2016 (1024)
        const float* g = w0g + (size_t)v * 2016;
        #pragma unroll
        for (int k = 0; k < 7; k++) dma16(g + k * 256 + lane * 4, Xb + k * 256);
        if (lane < 56) dma16(g + 1792 + lane * 4, Xb + 1792);
        const float* g1 = w1g + (size_t)v * 1024;
        #pragma unroll
        for (int k = 0; k < 4; k++) dma16(g1 + k * 256 + lane * 4, Xb + 2016 + k * 256);
    };
    auto dmaB = [&](int v, float* Xb) {          // vw@0, fw@1888, sw@2912, rw@2944
        const float* g = vwg + (size_t)v * 1888;
        #pragma unroll
        for (int k = 0; k < 7; k++) dma16(g + k * 256 + lane * 4, Xb + k * 256);
        if (lane < 24) dma16(g + 1792 + lane * 4, Xb + 1792);
        const float* g1 = fwg + (size_t)v * 1024;
        #pragma unroll
        for (int k = 0; k < 4; k++) dma16(g1 + k * 256 + lane * 4, Xb + 1888 + k * 256);
        if (lane < 8)  dma16(swg + (size_t)v * 32 + lane * 4, Xb + 2912);
        if (lane < 24) dma16(rwg + (size_t)v * 96 + lane * 4, Xb + 2944);
    };
#endif

    // ---- next-voxel prefetch state ----
    int c_n = 0, prow0_n = 0, prow1_n = 0;
    f4 cB0_n[2], cB1_n[2], cFB_n[2], cVB_n[2];
    float rb0_n = 0.f, rb1_n = 0.f, rb2_n = 0.f, sb_n = 0.f;
    int n0_n = 0;
    float px_n = 0.f, py_n = 0.f, pz_n = 0.f, dx_n = 0.f, dy_n = 0.f, dz_n = 0.f;

    auto pf_meta = [&](int v) {                  // independent loads, no chain
        c_n = min(count[v], CAP);
        prow0_n = plist[v * CAP + lane];
        prow1_n = plist[v * CAP + 64 + lane];
        #pragma unroll
        for (int Ti = 0; Ti < 2; Ti++) {
            int ro = v * 32 + Ti * 16 + quad * 4;
            cB0_n[Ti] = *(const f4*)(b0g + ro);
            cB1_n[Ti] = *(const f4*)(b1g + ro);
            cFB_n[Ti] = *(const f4*)(fbg + ro);
            cVB_n[Ti] = *(const f4*)(vbg + ro);
        }
        rb0_n = rbg[v * 3 + 0]; rb1_n = rbg[v * 3 + 1]; rb2_n = rbg[v * 3 + 2];
        sb_n  = sbg[v];
    };
    auto pf_pts = [&]() {                        // call only after prow_n landed
        if (c_n > 0) {
            int e = min(col, c_n - 1);           // e<=15 -> chunk0 uses prow0 only
            n0_n = __shfl(prow0_n, e);
            px_n = pts[3 * n0_n]; py_n = pts[3 * n0_n + 1]; pz_n = pts[3 * n0_n + 2];
            int ray = n0_n >> 7;
            dx_n = vds[3 * ray]; dy_n = vds[3 * ray + 1]; dz_n = vds[3 * ray + 2];
        }
    };

    // ---- prologue: voxel 0 meta + weights + chunk0 pts in flight ----
    pf_meta(vbase);
#if USE_DMA
    dmaA(vbase, X[0]);
#endif
    pf_pts();    // compiler-counted wait on plist; dmaA stays in flight

    h8 aW0[2][2], aW1[2], aVW[2][2], aFW[2], aSG, aRGB;
    h8 bE0, bE1, bD;
    const f4 z4 = {0.f, 0.f, 0.f, 0.f};

    auto encode = [&](float sx, float sy, float sz, float tx, float ty, float tz) {
        bE0 = pack8(encdim(k8 + 0, 63, sx, sy, sz), encdim(k8 + 1, 63, sx, sy, sz),
                    encdim(k8 + 2, 63, sx, sy, sz), encdim(k8 + 3, 63, sx, sy, sz),
                    encdim(k8 + 4, 63, sx, sy, sz), encdim(k8 + 5, 63, sx, sy, sz),
                    encdim(k8 + 6, 63, sx, sy, sz), encdim(k8 + 7, 63, sx, sy, sz));
        bE1 = pack8(encdim(32 + k8 + 0, 63, sx, sy, sz), encdim(32 + k8 + 1, 63, sx, sy, sz),
                    encdim(32 + k8 + 2, 63, sx, sy, sz), encdim(32 + k8 + 3, 63, sx, sy, sz),
                    encdim(32 + k8 + 4, 63, sx, sy, sz), encdim(32 + k8 + 5, 63, sx, sy, sz),
                    encdim(32 + k8 + 6, 63, sx, sy, sz), encdim(32 + k8 + 7, 63, sx, sy, sz));
        bD  = pack8(encdim(k8 + 0, 27, tx, ty, tz), encdim(k8 + 1, 27, tx, ty, tz),
                    encdim(k8 + 2, 27, tx, ty, tz), encdim(k8 + 3, 27, tx, ty, tz),
                    encdim(k8 + 4, 27, tx, ty, tz), encdim(k8 + 5, 27, tx, ty, tz),
                    encdim(k8 + 6, 27, tx, ty, tz), encdim(k8 + 7, 27, tx, ty, tz));
    };

    int cur = 0;
    for (int iv = 0; iv < NV; iv++) {
        float* Xb = X[cur];
        const int v = vbase + iv;

        // ---- snapshot prefetched state BEFORE any new prefetch (R10 lesson) ----
        const int c = c_n;
        const int prow0 = prow0_n, prow1 = prow1_n;
        f4 cB0[2] = {cB0_n[0], cB0_n[1]}, cB1[2] = {cB1_n[0], cB1_n[1]};
        f4 cFB[2] = {cFB_n[0], cFB_n[1]}, cVB[2] = {cVB_n[0], cVB_n[1]};
        const float rb0 = rb0_n, rb1 = rb1_n, rb2 = rb2_n, sb = sb_n;
        const int n0 = n0_n;
        const float px = px_n, py = py_n, pz = pz_n;
        const float dx = dx_n, dy = dy_n, dz = dz_n;
        const bool hasW = c > 0;

        auto chunk_idx = [&](int base) -> int {
            int e = min(base + col, c - 1);
            int a = __shfl(prow0, e);
            int b = __shfl(prow1, e - 64);
            return (e < 64) ? a : b;
        };

#if USE_DMA
        asm volatile("s_waitcnt vmcnt(0)" ::: "memory");   // A(iv)+prefetch landed
        __builtin_amdgcn_sched_barrier(0);

        // unpack A (ds_reads on X[cur])
        if (hasW) {
            #pragma unroll
            for (int Ti = 0; Ti < 2; Ti++) {
                int r0 = (Ti * 16 + col) * 63;
                aW0[Ti][0] = lds_row8(Xb, r0, k8, 63);
                aW0[Ti][1] = lds_row8(Xb, r0, 32 + k8, 63);
                aW1[Ti] = lds_row8a(Xb, 2016 + (Ti * 16 + col) * 32 + k8);
            }
        }
#else
        if (hasW) {
            #pragma unroll
            for (int Ti = 0; Ti < 2; Ti++) {
                const float* rb = w0g + (size_t)v * 2016 + (Ti * 16 + col) * 63;
                aW0[Ti][0] = load_row8(rb, k8, 63);
                aW0[Ti][1] = load_row8(rb, 32 + k8, 63);
                aW1[Ti] = load_row8(w1g + (size_t)v * 1024 + (Ti * 16 + col) * 32, k8, 32);
            }
        }
#endif

        // chunk-1 gather for CURRENT voxel (VMEM; lands by the mid-drain)
        int n1 = 0;
        float qx = 0.f, qy = 0.f, qz = 0.f, ex = 0.f, ey = 0.f, ez = 0.f;
        if (c > 16) {
            n1 = chunk_idx(16);
            qx = pts[3 * n1]; qy = pts[3 * n1 + 1]; qz = pts[3 * n1 + 2];
            int r2 = n1 >> 7;
            ex = vds[3 * r2]; ey = vds[3 * r2 + 1]; ez = vds[3 * r2 + 2];
        }

        // next voxel's independent meta loads (before any DMA -> never drained late)
        if (iv + 1 < NV) pf_meta(v + 1);

#if USE_DMA
        asm volatile("s_waitcnt lgkmcnt(0)" ::: "memory"); // A-reads retired (WAR)
        __builtin_amdgcn_sched_barrier(0);
        dmaB(v, Xb);                                       // overwrite X[cur] with B stage
#endif

        f4 d0, d1, e0, e1;
        h8 bH, bG;
        if (hasW) {
            encode(px, py, pz, dx, dy, dz);
            // phase A: layers 0/1 (A-frags only) — covers B-DMA flight
            d0 = MF(aW0[0][0], bE0, cB0[0]); d0 = MF(aW0[0][1], bE1, d0);
            d1 = MF(aW0[1][0], bE0, cB0[1]); d1 = MF(aW0[1][1], bE1, d1);
            d0 = relu4(d0); d1 = relu4(d1);
            bH = makeB(d0, d1, quad, col);
            e0 = MF(aW1[0], bH, cB1[0]);
            e1 = MF(aW1[1], bH, cB1[1]);
            e0 = relu4(e0); e1 = relu4(e1);
            bG = makeB(e0, e1, quad, col);
        }

#if USE_DMA
        __builtin_amdgcn_sched_barrier(0);
        asm volatile("s_waitcnt vmcnt(0)" ::: "memory");   // B landed (+ch1, meta)
        __builtin_amdgcn_sched_barrier(0);

        // unpack B (ds_reads on X[cur])
        if (hasW) {
            #pragma unroll
            for (int Ti = 0; Ti < 2; Ti++) {
                int r1 = (Ti * 16 + col) * 59;
                aVW[Ti][0] = lds_row8(Xb, r1, k8, 59);
                aVW[Ti][1] = lds_row8(Xb, r1, 32 + k8, 59);
                aFW[Ti] = lds_row8a(Xb, 1888 + (Ti * 16 + col) * 32 + k8);
            }
            aSG  = (col == 0) ? lds_row8a(Xb, 2912 + k8) : h8{};
            aRGB = (col < 3) ? lds_row8a(Xb, 2944 + col * 32 + k8) : h8{};
        }
#else
        if (hasW) {
            #pragma unroll
            for (int Ti = 0; Ti < 2; Ti++) {
                const float* rb = vwg + (size_t)v * 1888 + (Ti * 16 + col) * 59;
                aVW[Ti][0] = load_row8(rb, k8, 59);
                aVW[Ti][1] = load_row8(rb, 32 + k8, 59);
                aFW[Ti] = load_row8(fwg + (size_t)v * 1024 + (Ti * 16 + col) * 32, k8, 32);
            }
            aSG  = (col == 0) ? load_row8(swg + (size_t)v * 32, k8, 32) : h8{};
            aRGB = (col < 3) ? load_row8(rwg + (size_t)v * 96 + col * 32, k8, 32) : h8{};
        }
#endif

        // next voxel: dependent pts-chain (prow_n landed at the drain above),
        // then A-DMA LAST so no later compiler wait ever drains it.
        if (iv + 1 < NV) {
            pf_pts();
#if USE_DMA
            dmaA(v + 1, X[cur ^ 1]);
#endif
        }

        if (hasW) {
            // ---- phase B, chunk 0 ----
            {
                f4 s  = MF(aSG, bG, z4);
                f4 f0 = MF(aFW[0], bG, cFB[0]);
                f4 f1 = MF(aFW[1], bG, cFB[1]);
                h8 bF = makeB(f0, f1, quad, col);
                f4 v0 = MF(aVW[0][0], bF, cVB[0]); v0 = MF(aVW[0][1], bD, v0);
                f4 v1 = MF(aVW[1][0], bF, cVB[1]); v1 = MF(aVW[1][1], bD, v1);
                v0 = relu4(v0); v1 = relu4(v1);
                h8 bV = makeB(v0, v1, quad, col);
                f4 o  = MF(aRGB, bV, z4);
                if (quad == 0 && col < c) {
                    out[3 * n0 + 0] = o[0] + rb0;
                    out[3 * n0 + 1] = o[1] + rb1;
                    out[3 * n0 + 2] = o[2] + rb2;
                    out[3 * NPTS + n0] = s[0] + sb;
                }
            }

            auto do_chunk = [&](int n, bool active) {
                d0 = MF(aW0[0][0], bE0, cB0[0]); d0 = MF(aW0[0][1], bE1, d0);
                d1 = MF(aW0[1][0], bE0, cB0[1]); d1 = MF(aW0[1][1], bE1, d1);
                d0 = relu4(d0); d1 = relu4(d1);
                bH = makeB(d0, d1, quad, col);
                e0 = MF(aW1[0], bH, cB1[0]);
                e1 = MF(aW1[1], bH, cB1[1]);
                e0 = relu4(e0); e1 = relu4(e1);
                bG = makeB(e0, e1, quad, col);
                f4 s  = MF(aSG, bG, z4);
                f4 f0 = MF(aFW[0], bG, cFB[0]);
                f4 f1 = MF(aFW[1], bG, cFB[1]);
                h8 bF = makeB(f0, f1, quad, col);
                f4 v0 = MF(aVW[0][0], bF, cVB[0]); v0 = MF(aVW[0][1], bD, v0);
                f4 v1 = MF(aVW[1][0], bF, cVB[1]); v1 = MF(aVW[1][1], bD, v1);
                v0 = relu4(v0); v1 = relu4(v1);
                h8 bV = makeB(v0, v1, quad, col);
                f4 o  = MF(aRGB, bV, z4);
                if (quad == 0 && active) {
                    out[3 * n + 0] = o[0] + rb0;
                    out[3 * n + 1] = o[1] + rb1;
                    out[3 * n + 2] = o[2] + rb2;
                    out[3 * NPTS + n] = s[0] + sb;
                }
            };

            // ---- chunk 1 (data gathered before B-DMA; landed at mid-drain) ----
            if (c > 16) {
                encode(qx, qy, qz, ex, ey, ez);
                do_chunk(n1, (16 + col) < c);
            }
            // ---- chunks 2+ (inline gathers; may partially drain A(iv+1)) ----
            for (int base = 32; base < c; base += 16) {
                int n = chunk_idx(base);
                float gx = pts[3 * n], gy = pts[3 * n + 1], gz = pts[3 * n + 2];
                int r3 = n >> 7;
                float hx = vds[3 * r3], hy = vds[3 * r3 + 1], hz = vds[3 * r3 + 2];
                encode(gx, gy, gz, hx, hy, hz);
                do_chunk(n, (base + col) < c);
            }
        }

        cur ^= 1;
    }
}

extern "C" void kernel_launch(void* const* d_in, const int* in_sizes, int n_in,
                              void* d_out, int out_size, void* d_ws, size_t ws_size,
                              hipStream_t stream) {
    const float* pts = (const float*)d_in[0];
    const float* vds = (const float*)d_in[1];
    const float* w0  = (const float*)d_in[2];
    const float* b0  = (const float*)d_in[3];
    const float* w1  = (const float*)d_in[4];
    const float* b1  = (const float*)d_in[5];
    const float* fw  = (const float*)d_in[6];
    const float* fb  = (const float*)d_in[7];
    const float* sw  = (const float*)d_in[8];
    const float* sb  = (const float*)d_in[9];
    const float* vw  = (const float*)d_in[10];
    const float* vb  = (const float*)d_in[11];
    const float* rw  = (const float*)d_in[12];
    const float* rb  = (const float*)d_in[13];
    float* out = (float*)d_out;

    int* count = (int*)d_ws;
    int* plist = (int*)((char*)d_ws + NM * sizeof(int));

    (void)hipMemsetAsync(count, 0, NM * sizeof(int), stream);
    k_bucket<<<NPTS / 256, 256, 0, stream>>>(pts, count, plist);
    k_mlp<<<NBLK, 64, 0, stream>>>(pts, vds, w0, b0, w1, b1, fw, fb, sw, sb,
                                   vw, vb, rw, rb, count, plist, out);
}